// Round 3
// baseline (558.045 us; speedup 1.0000x reference)
//
#include <hip/hip_runtime.h>
#include <hip/hip_bf16.h>

// SimpleMoE: B=2,S=2048 -> 4096 tokens, DIM=1024, FF=4096, E=8, top-2 routing.
// Round 3: double-buffered (2-phase) grouped GEMMs with asm ds_read_b128
// fragment loads + split-K=4 gemm2 for occupancy.

typedef __attribute__((ext_vector_type(8))) short bf16x8;
typedef __attribute__((ext_vector_type(4))) float f32x4;

__device__ __forceinline__ unsigned short f2bf(float f) {
  unsigned u = __builtin_bit_cast(unsigned, f);
  u += 0x7FFFu + ((u >> 16) & 1u);
  return (unsigned short)(u >> 16);
}

__device__ __forceinline__ void gload_lds16(const void* g, void* l) {
  __builtin_amdgcn_global_load_lds(
      (const __attribute__((address_space(1))) unsigned int*)g,
      (__attribute__((address_space(3))) unsigned int*)l, 16, 0, 0);
}

// inline-asm LDS read: keeps the compiler from serializing ds_read behind
// in-flight global_load_lds (false alias) with a vmcnt(0).
__device__ __forceinline__ bf16x8 ldsr128(const unsigned short* p) {
  bf16x8 r;
  unsigned a = (unsigned)(unsigned long long)p;
  asm volatile("ds_read_b128 %0, %1" : "=v"(r) : "v"(a));
  return r;
}

// ---------------- gate: logits (fp64), softmax, top-2, counts ----------------
__global__ __launch_bounds__(256) void gate_kernel(
    const float* __restrict__ x, const float* __restrict__ Wg,
    const float* __restrict__ bg, int* __restrict__ tok_e,
    float* __restrict__ tok_w, int* __restrict__ counts) {
  const int wave = threadIdx.x >> 6;
  const int lane = threadIdx.x & 63;
  const int t = blockIdx.x * 4 + wave;
  const float* xr = x + (size_t)t * 1024;
  double acc[8] = {0, 0, 0, 0, 0, 0, 0, 0};
  for (int i = 0; i < 16; ++i) {
    const int d = i * 64 + lane;
    const double xv = (double)xr[d];
    const float* wr = Wg + d * 8;
#pragma unroll
    for (int e = 0; e < 8; ++e) acc[e] += xv * (double)wr[e];
  }
#pragma unroll
  for (int e = 0; e < 8; ++e) {
    double v = acc[e];
#pragma unroll
    for (int off = 32; off > 0; off >>= 1) v += __shfl_xor(v, off, 64);
    acc[e] = v + (double)bg[e];
  }
  if (lane == 0) {
    int e0 = 0;
#pragma unroll
    for (int e = 1; e < 8; ++e)
      if (acc[e] > acc[e0]) e0 = e;
    int e1 = (e0 == 0) ? 1 : 0;
#pragma unroll
    for (int e = 0; e < 8; ++e) {
      if (e != e0 && acc[e] > acc[e1]) e1 = e;
    }
    const double m = acc[e0];
    double s = 0.0;
#pragma unroll
    for (int e = 0; e < 8; ++e) s += exp(acc[e] - m);
    const double p0 = exp(acc[e0] - m) / s;
    const double p1 = exp(acc[e1] - m) / s;
    const double den = p0 + p1 + 1e-9;
    tok_e[2 * t] = e0;
    tok_e[2 * t + 1] = e1;
    tok_w[2 * t] = (float)(p0 / den);
    tok_w[2 * t + 1] = (float)(p1 / den);
    atomicAdd(&counts[e0], 1);
    atomicAdd(&counts[e1], 1);
  }
}

__global__ void scan_kernel(const int* __restrict__ counts,
                            int* __restrict__ offsets,
                            int* __restrict__ cursors) {
  if (threadIdx.x == 0) {
    int s = 0;
    for (int e = 0; e < 8; ++e) {
      offsets[e] = s;
      cursors[e] = s;
      s += counts[e];
    }
  }
}

__global__ __launch_bounds__(256) void scatter_kernel(
    const int* __restrict__ tok_e, const float* __restrict__ tok_w,
    int* __restrict__ cursors, int* __restrict__ pair_token,
    float* __restrict__ pair_w) {
  const int t = blockIdx.x * 256 + threadIdx.x;
  if (t >= 4096) return;
#pragma unroll
  for (int j = 0; j < 2; ++j) {
    const int e = tok_e[2 * t + j];
    const int slot = atomicAdd(&cursors[e], 1);
    pair_token[slot] = t;
    pair_w[slot] = tok_w[2 * t + j];
  }
}

// ---------------- x -> bf16 ----------------
__global__ __launch_bounds__(256) void xconv_kernel(
    const float* __restrict__ x, unsigned short* __restrict__ xb) {
  const size_t i = ((size_t)blockIdx.x * 256 + threadIdx.x) * 4;
  const float4 v = *(const float4*)(x + i);
  ushort4 pk;
  pk.x = f2bf(v.x); pk.y = f2bf(v.y); pk.z = f2bf(v.z); pk.w = f2bf(v.w);
  *(ushort4*)(xb + i) = pk;
}

// ---------------- W1[e][k][f] -> W1t[e][f_local][k] (bf16) ----------------
__global__ __launch_bounds__(256) void transW1_kernel(
    const float* __restrict__ W1, unsigned short* __restrict__ W1t, int FC,
    int f0) {
  const int e = blockIdx.z;
  const int fl = blockIdx.x * 64 + (threadIdx.x & 63);
  const int kg = threadIdx.x >> 6;
  const int kbase = (blockIdx.y * 4 + kg) * 32;
  const float* src = W1 + ((size_t)e * 1024 + kbase) * 4096 + f0 + fl;
  unsigned short* dst = W1t + ((size_t)e * FC + fl) * 1024 + kbase;
  for (int i = 0; i < 8; ++i) {
    ushort4 pk;
    pk.x = f2bf(src[(size_t)(i * 4 + 0) * 4096]);
    pk.y = f2bf(src[(size_t)(i * 4 + 1) * 4096]);
    pk.z = f2bf(src[(size_t)(i * 4 + 2) * 4096]);
    pk.w = f2bf(src[(size_t)(i * 4 + 3) * 4096]);
    *(ushort4*)&dst[i * 4] = pk;
  }
}

// ---------------- W2[e][f][d] -> W2t[e][d][f_local] (bf16) ----------------
__global__ __launch_bounds__(256) void transW2_kernel(
    const float* __restrict__ W2, unsigned short* __restrict__ W2t, int FC,
    int f0) {
  const int e = blockIdx.z;
  const int dl = blockIdx.x * 64 + (threadIdx.x & 63);
  const int fg = threadIdx.x >> 6;
  const int fbase = (blockIdx.y * 4 + fg) * 32;
  const float* src = W2 + ((size_t)e * 4096 + f0 + fbase) * 1024 + dl;
  unsigned short* dst = W2t + ((size_t)e * 1024 + dl) * FC + fbase;
  for (int i = 0; i < 8; ++i) {
    ushort4 pk;
    pk.x = f2bf(src[(size_t)(i * 4 + 0) * 1024]);
    pk.y = f2bf(src[(size_t)(i * 4 + 1) * 1024]);
    pk.z = f2bf(src[(size_t)(i * 4 + 2) * 1024]);
    pk.w = f2bf(src[(size_t)(i * 4 + 3) * 1024]);
    *(ushort4*)&dst[i * 4] = pk;
  }
}

// ---------------- GEMM1: H[slot][n] = relu(xb[tok] @ W1t[e] + b1) -----------
// 128x128 tile, BK=32, 4 waves 2x2, double-buffered LDS (2-phase).
__global__ __launch_bounds__(256) void gemm1_kernel(
    const unsigned short* __restrict__ xb,
    const unsigned short* __restrict__ W1t, const float* __restrict__ b1,
    const int* __restrict__ counts, const int* __restrict__ offsets,
    const int* __restrict__ pair_token, unsigned short* __restrict__ H, int FC,
    int f0) {
  const int e = blockIdx.z;
  const int count = counts[e];
  const int m0 = blockIdx.y * 128;
  if (m0 >= count) return;
  const int offset = offsets[e];
  const int n0 = blockIdx.x * 128;

  __shared__ __align__(16) unsigned short Alds[2][128 * 32];
  __shared__ __align__(16) unsigned short Blds[2][128 * 32];
  __shared__ int toklds[128];

  const int tid = threadIdx.x;
  if (tid < 128) {
    int r = m0 + tid;
    if (r >= count) r = count - 1;
    toklds[tid] = pair_token[offset + r];
  }
  __syncthreads();

  const int lane = tid & 63;
  const int wave = tid >> 6;
  const int srow = lane >> 2;
  const int skp = (lane & 3) * 8;
  const unsigned short* aga[2];
  const unsigned short* bga[2];
  int ldso[2];
#pragma unroll
  for (int i = 0; i < 2; ++i) {
    const int ar = wave * 32 + i * 16 + srow;
    aga[i] = xb + (size_t)toklds[ar] * 1024 + skp;
    bga[i] = W1t + ((size_t)e * FC + n0 + wave * 32 + i * 16 + srow) * 1024 + skp;
    ldso[i] = (wave * 32 + i * 16) * 32;
  }

  const int wm = (wave >> 1) * 64;
  const int wn = (wave & 1) * 64;
  const int l16 = lane & 15;
  const int lk = lane >> 4;

  f32x4 acc[4][4] = {};

  auto STAGE = [&](int kt, int buf) {
#pragma unroll
    for (int i = 0; i < 2; ++i) {
      gload_lds16(aga[i] + kt, &Alds[buf][ldso[i]]);
      gload_lds16(bga[i] + kt, &Blds[buf][ldso[i]]);
    }
  };
  auto COMPUTE = [&](int buf) {
    bf16x8 af[4], bfr[4];
#pragma unroll
    for (int mi = 0; mi < 4; ++mi)
      af[mi] = ldsr128(&Alds[buf][(wm + mi * 16 + l16) * 32 + lk * 8]);
#pragma unroll
    for (int nj = 0; nj < 4; ++nj)
      bfr[nj] = ldsr128(&Blds[buf][(wn + nj * 16 + l16) * 32 + lk * 8]);
    asm volatile("s_waitcnt lgkmcnt(0)" ::: "memory");
    __builtin_amdgcn_sched_barrier(0);
#pragma unroll
    for (int mi = 0; mi < 4; ++mi)
#pragma unroll
      for (int nj = 0; nj < 4; ++nj)
        acc[mi][nj] = __builtin_amdgcn_mfma_f32_16x16x32_bf16(
            af[mi], bfr[nj], acc[mi][nj], 0, 0, 0);
  };

  STAGE(0, 0);
  __syncthreads();
  int cur = 0;
  for (int t = 0; t < 31; ++t) {
    STAGE((t + 1) * 32, cur ^ 1);
    COMPUTE(cur);
    __syncthreads();
    cur ^= 1;
  }
  COMPUTE(cur);

#pragma unroll
  for (int mi = 0; mi < 4; ++mi) {
#pragma unroll
    for (int r = 0; r < 4; ++r) {
      const int rl = m0 + wm + mi * 16 + lk * 4 + r;
      if (rl >= count) continue;
      unsigned short* hrow = H + (size_t)(offset + rl) * FC;
#pragma unroll
      for (int nj = 0; nj < 4; ++nj) {
        const int c = n0 + wn + nj * 16 + l16;
        float v = acc[mi][nj][r] + b1[e * 4096 + f0 + c];
        hrow[c] = f2bf(v > 0.f ? v : 0.f);
      }
    }
  }
}

// ---------------- GEMM2: out[tok] += w * (H @ W2t[e] + b2), split-K ---------
__global__ __launch_bounds__(256) void gemm2_kernel(
    const unsigned short* __restrict__ H,
    const unsigned short* __restrict__ W2t, const float* __restrict__ b2,
    const int* __restrict__ counts, const int* __restrict__ offsets,
    const int* __restrict__ pair_token, const float* __restrict__ pair_w,
    float* __restrict__ out, int FC, int addBias) {
  const int e = blockIdx.z >> 2;
  const int ks = blockIdx.z & 3;
  const int count = counts[e];
  const int m0 = blockIdx.y * 128;
  if (m0 >= count) return;
  const int offset = offsets[e];
  const int n0 = blockIdx.x * 128;
  const int KS = FC / 4;      // K slice length
  const int kb = ks * KS;     // K slice base

  __shared__ __align__(16) unsigned short Alds[2][128 * 32];
  __shared__ __align__(16) unsigned short Blds[2][128 * 32];
  __shared__ int toklds[128];
  __shared__ float wlds[128];

  const int tid = threadIdx.x;
  if (tid < 128) {
    int r = m0 + tid;
    if (r >= count) r = count - 1;
    toklds[tid] = pair_token[offset + r];
    wlds[tid] = pair_w[offset + r];
  }
  __syncthreads();

  const int lane = tid & 63;
  const int wave = tid >> 6;
  const int srow = lane >> 2;
  const int skp = (lane & 3) * 8;
  const unsigned short* aga[2];
  const unsigned short* bga[2];
  int ldso[2];
#pragma unroll
  for (int i = 0; i < 2; ++i) {
    int ar = m0 + wave * 32 + i * 16 + srow;
    if (ar >= count) ar = count - 1;
    aga[i] = H + (size_t)(offset + ar) * FC + kb + skp;
    bga[i] = W2t + ((size_t)e * 1024 + n0 + wave * 32 + i * 16 + srow) * FC + kb + skp;
    ldso[i] = (wave * 32 + i * 16) * 32;
  }

  const int wm = (wave >> 1) * 64;
  const int wn = (wave & 1) * 64;
  const int l16 = lane & 15;
  const int lk = lane >> 4;

  f32x4 acc[4][4] = {};

  auto STAGE = [&](int kt, int buf) {
#pragma unroll
    for (int i = 0; i < 2; ++i) {
      gload_lds16(aga[i] + kt, &Alds[buf][ldso[i]]);
      gload_lds16(bga[i] + kt, &Blds[buf][ldso[i]]);
    }
  };
  auto COMPUTE = [&](int buf) {
    bf16x8 af[4], bfr[4];
#pragma unroll
    for (int mi = 0; mi < 4; ++mi)
      af[mi] = ldsr128(&Alds[buf][(wm + mi * 16 + l16) * 32 + lk * 8]);
#pragma unroll
    for (int nj = 0; nj < 4; ++nj)
      bfr[nj] = ldsr128(&Blds[buf][(wn + nj * 16 + l16) * 32 + lk * 8]);
    asm volatile("s_waitcnt lgkmcnt(0)" ::: "memory");
    __builtin_amdgcn_sched_barrier(0);
#pragma unroll
    for (int mi = 0; mi < 4; ++mi)
#pragma unroll
      for (int nj = 0; nj < 4; ++nj)
        acc[mi][nj] = __builtin_amdgcn_mfma_f32_16x16x32_bf16(
            af[mi], bfr[nj], acc[mi][nj], 0, 0, 0);
  };

  const int NT = KS / 32;
  STAGE(0, 0);
  __syncthreads();
  int cur = 0;
  for (int t = 0; t < NT - 1; ++t) {
    STAGE((t + 1) * 32, cur ^ 1);
    COMPUTE(cur);
    __syncthreads();
    cur ^= 1;
  }
  COMPUTE(cur);

#pragma unroll
  for (int mi = 0; mi < 4; ++mi) {
#pragma unroll
    for (int r = 0; r < 4; ++r) {
      const int rloc = wm + mi * 16 + lk * 4 + r;
      const int rl = m0 + rloc;
      if (rl >= count) continue;
      const int tok = toklds[rloc];
      const float wgt = wlds[rloc];
      float* orow = out + (size_t)tok * 1024;
#pragma unroll
      for (int nj = 0; nj < 4; ++nj) {
        const int c = n0 + wn + nj * 16 + l16;
        float v = acc[mi][nj][r];
        if (addBias && ks == 0) v += b2[e * 1024 + c];
        unsafeAtomicAdd(&orow[c], v * wgt);
      }
    }
  }
}

extern "C" void kernel_launch(void* const* d_in, const int* in_sizes, int n_in,
                              void* d_out, int out_size, void* d_ws,
                              size_t ws_size, hipStream_t stream) {
  const float* x = (const float*)d_in[0];
  const float* Wg = (const float*)d_in[1];
  const float* bg = (const float*)d_in[2];
  const float* W1 = (const float*)d_in[3];
  const float* b1 = (const float*)d_in[4];
  const float* W2 = (const float*)d_in[5];
  const float* b2 = (const float*)d_in[6];
  float* out = (float*)d_out;

  char* w = (char*)d_ws;
  int* counts = (int*)w;
  int* offsets = counts + 16;
  int* cursors = counts + 32;
  int* tok_e = (int*)(w + 1024);
  float* tok_w = (float*)(w + 1024 + 32768);
  int* pair_token = (int*)(w + 1024 + 65536);
  float* pair_w = (float*)(w + 1024 + 98304);
  unsigned short* xb = (unsigned short*)(w + 256 * 1024);
  char* big = w + 256 * 1024 + 8 * 1024 * 1024;
  const size_t avail = ws_size - (256 * 1024 + 8 * 1024 * 1024);

  int FC = 4096;
  while (FC > 256 && (size_t)FC * 49152 > avail) FC >>= 1;

  unsigned short* W1t = (unsigned short*)big;
  unsigned short* W2t = W1t + (size_t)8 * FC * 1024;
  unsigned short* Hc = W2t + (size_t)8 * 1024 * FC;

  hipMemsetAsync(counts, 0, 64, stream);
  hipMemsetAsync(d_out, 0, (size_t)out_size * 4, stream);

  gate_kernel<<<1024, 256, 0, stream>>>(x, Wg, bg, tok_e, tok_w, counts);
  scan_kernel<<<1, 64, 0, stream>>>(counts, offsets, cursors);
  scatter_kernel<<<16, 256, 0, stream>>>(tok_e, tok_w, cursors, pair_token,
                                         pair_w);
  xconv_kernel<<<4096, 256, 0, stream>>>(x, xb);

  for (int f0 = 0; f0 < 4096; f0 += FC) {
    transW1_kernel<<<dim3(FC / 64, 8, 8), 256, 0, stream>>>(W1, W1t, FC, f0);
    transW2_kernel<<<dim3(16, FC / 128, 8), 256, 0, stream>>>(W2, W2t, FC, f0);
    gemm1_kernel<<<dim3(FC / 128, 32, 8), 256, 0, stream>>>(
        xb, W1t, b1, counts, offsets, pair_token, Hc, FC, f0);
    gemm2_kernel<<<dim3(8, 32, 32), 256, 0, stream>>>(
        Hc, W2t, b2, counts, offsets, pair_token, pair_w, out, FC,
        f0 == 0 ? 1 : 0);
  }
}

// Round 4
// 515.743 us; speedup vs baseline: 1.0820x; 1.0820x over previous
//
#include <hip/hip_runtime.h>
#include <hip/hip_bf16.h>

// SimpleMoE: B=2,S=2048 -> 4096 tokens, DIM=1024, FF=4096, E=8, top-2 routing.
// Round 4: atomic-free gemm2 (split-K=2 into private fp32 partial buffers) +
// combine kernel. 2-phase double-buffered grouped GEMMs, gload_lds staging.

typedef __attribute__((ext_vector_type(8))) short bf16x8;
typedef __attribute__((ext_vector_type(4))) float f32x4;

__device__ __forceinline__ unsigned short f2bf(float f) {
  unsigned u = __builtin_bit_cast(unsigned, f);
  u += 0x7FFFu + ((u >> 16) & 1u);
  return (unsigned short)(u >> 16);
}

__device__ __forceinline__ void gload_lds16(const void* g, void* l) {
  __builtin_amdgcn_global_load_lds(
      (const __attribute__((address_space(1))) unsigned int*)g,
      (__attribute__((address_space(3))) unsigned int*)l, 16, 0, 0);
}

// inline-asm LDS read: keeps the compiler from serializing ds_read behind
// in-flight global_load_lds (false alias) with a vmcnt(0).
__device__ __forceinline__ bf16x8 ldsr128(const unsigned short* p) {
  bf16x8 r;
  unsigned a = (unsigned)(unsigned long long)p;
  asm volatile("ds_read_b128 %0, %1" : "=v"(r) : "v"(a));
  return r;
}

// ---------------- gate: logits (fp64), softmax, top-2, counts ----------------
__global__ __launch_bounds__(256) void gate_kernel(
    const float* __restrict__ x, const float* __restrict__ Wg,
    const float* __restrict__ bg, int* __restrict__ tok_e,
    float* __restrict__ tok_w, int* __restrict__ counts) {
  const int wave = threadIdx.x >> 6;
  const int lane = threadIdx.x & 63;
  const int t = blockIdx.x * 4 + wave;
  const float* xr = x + (size_t)t * 1024;
  double acc[8] = {0, 0, 0, 0, 0, 0, 0, 0};
  for (int i = 0; i < 16; ++i) {
    const int d = i * 64 + lane;
    const double xv = (double)xr[d];
    const float* wr = Wg + d * 8;
#pragma unroll
    for (int e = 0; e < 8; ++e) acc[e] += xv * (double)wr[e];
  }
#pragma unroll
  for (int e = 0; e < 8; ++e) {
    double v = acc[e];
#pragma unroll
    for (int off = 32; off > 0; off >>= 1) v += __shfl_xor(v, off, 64);
    acc[e] = v + (double)bg[e];
  }
  if (lane == 0) {
    int e0 = 0;
#pragma unroll
    for (int e = 1; e < 8; ++e)
      if (acc[e] > acc[e0]) e0 = e;
    int e1 = (e0 == 0) ? 1 : 0;
#pragma unroll
    for (int e = 0; e < 8; ++e) {
      if (e != e0 && acc[e] > acc[e1]) e1 = e;
    }
    const double m = acc[e0];
    double s = 0.0;
#pragma unroll
    for (int e = 0; e < 8; ++e) s += exp(acc[e] - m);
    const double p0 = exp(acc[e0] - m) / s;
    const double p1 = exp(acc[e1] - m) / s;
    const double den = p0 + p1 + 1e-9;
    tok_e[2 * t] = e0;
    tok_e[2 * t + 1] = e1;
    tok_w[2 * t] = (float)(p0 / den);
    tok_w[2 * t + 1] = (float)(p1 / den);
    atomicAdd(&counts[e0], 1);
    atomicAdd(&counts[e1], 1);
  }
}

__global__ void scan_kernel(const int* __restrict__ counts,
                            int* __restrict__ offsets,
                            int* __restrict__ cursors) {
  if (threadIdx.x == 0) {
    int s = 0;
    for (int e = 0; e < 8; ++e) {
      offsets[e] = s;
      cursors[e] = s;
      s += counts[e];
    }
  }
}

__global__ __launch_bounds__(256) void scatter_kernel(
    const int* __restrict__ tok_e, int* __restrict__ cursors,
    int* __restrict__ pair_token, int* __restrict__ tok_slot) {
  const int t = blockIdx.x * 256 + threadIdx.x;
  if (t >= 4096) return;
#pragma unroll
  for (int j = 0; j < 2; ++j) {
    const int e = tok_e[2 * t + j];
    const int slot = atomicAdd(&cursors[e], 1);
    pair_token[slot] = t;
    tok_slot[2 * t + j] = slot;
  }
}

// ---------------- x -> bf16 ----------------
__global__ __launch_bounds__(256) void xconv_kernel(
    const float* __restrict__ x, unsigned short* __restrict__ xb) {
  const size_t i = ((size_t)blockIdx.x * 256 + threadIdx.x) * 4;
  const float4 v = *(const float4*)(x + i);
  ushort4 pk;
  pk.x = f2bf(v.x); pk.y = f2bf(v.y); pk.z = f2bf(v.z); pk.w = f2bf(v.w);
  *(ushort4*)(xb + i) = pk;
}

// ---------------- W1[e][k][f] -> W1t[e][f_local][k] (bf16) ----------------
__global__ __launch_bounds__(256) void transW1_kernel(
    const float* __restrict__ W1, unsigned short* __restrict__ W1t, int FC,
    int f0) {
  const int e = blockIdx.z;
  const int fl = blockIdx.x * 64 + (threadIdx.x & 63);
  const int kg = threadIdx.x >> 6;
  const int kbase = (blockIdx.y * 4 + kg) * 32;
  const float* src = W1 + ((size_t)e * 1024 + kbase) * 4096 + f0 + fl;
  unsigned short* dst = W1t + ((size_t)e * FC + fl) * 1024 + kbase;
  for (int i = 0; i < 8; ++i) {
    ushort4 pk;
    pk.x = f2bf(src[(size_t)(i * 4 + 0) * 4096]);
    pk.y = f2bf(src[(size_t)(i * 4 + 1) * 4096]);
    pk.z = f2bf(src[(size_t)(i * 4 + 2) * 4096]);
    pk.w = f2bf(src[(size_t)(i * 4 + 3) * 4096]);
    *(ushort4*)&dst[i * 4] = pk;
  }
}

// ---------------- W2[e][f][d] -> W2t[e][d][f_local] (bf16) ----------------
__global__ __launch_bounds__(256) void transW2_kernel(
    const float* __restrict__ W2, unsigned short* __restrict__ W2t, int FC,
    int f0) {
  const int e = blockIdx.z;
  const int dl = blockIdx.x * 64 + (threadIdx.x & 63);
  const int fg = threadIdx.x >> 6;
  const int fbase = (blockIdx.y * 4 + fg) * 32;
  const float* src = W2 + ((size_t)e * 4096 + f0 + fbase) * 1024 + dl;
  unsigned short* dst = W2t + ((size_t)e * 1024 + dl) * FC + fbase;
  for (int i = 0; i < 8; ++i) {
    ushort4 pk;
    pk.x = f2bf(src[(size_t)(i * 4 + 0) * 1024]);
    pk.y = f2bf(src[(size_t)(i * 4 + 1) * 1024]);
    pk.z = f2bf(src[(size_t)(i * 4 + 2) * 1024]);
    pk.w = f2bf(src[(size_t)(i * 4 + 3) * 1024]);
    *(ushort4*)&dst[i * 4] = pk;
  }
}

// ---------------- GEMM1: H[slot][n] = relu(xb[tok] @ W1t[e] + b1) -----------
__global__ __launch_bounds__(256) void gemm1_kernel(
    const unsigned short* __restrict__ xb,
    const unsigned short* __restrict__ W1t, const float* __restrict__ b1,
    const int* __restrict__ counts, const int* __restrict__ offsets,
    const int* __restrict__ pair_token, unsigned short* __restrict__ H, int FC,
    int f0) {
  const int e = blockIdx.z;
  const int count = counts[e];
  const int m0 = blockIdx.y * 128;
  if (m0 >= count) return;
  const int offset = offsets[e];
  const int n0 = blockIdx.x * 128;

  __shared__ __align__(16) unsigned short Alds[2][128 * 32];
  __shared__ __align__(16) unsigned short Blds[2][128 * 32];
  __shared__ int toklds[128];

  const int tid = threadIdx.x;
  if (tid < 128) {
    int r = m0 + tid;
    if (r >= count) r = count - 1;
    toklds[tid] = pair_token[offset + r];
  }
  __syncthreads();

  const int lane = tid & 63;
  const int wave = tid >> 6;
  const int srow = lane >> 2;
  const int skp = (lane & 3) * 8;
  const unsigned short* aga[2];
  const unsigned short* bga[2];
  int ldso[2];
#pragma unroll
  for (int i = 0; i < 2; ++i) {
    const int ar = wave * 32 + i * 16 + srow;
    aga[i] = xb + (size_t)toklds[ar] * 1024 + skp;
    bga[i] = W1t + ((size_t)e * FC + n0 + wave * 32 + i * 16 + srow) * 1024 + skp;
    ldso[i] = (wave * 32 + i * 16) * 32;
  }

  const int wm = (wave >> 1) * 64;
  const int wn = (wave & 1) * 64;
  const int l16 = lane & 15;
  const int lk = lane >> 4;

  f32x4 acc[4][4] = {};

  auto STAGE = [&](int kt, int buf) {
#pragma unroll
    for (int i = 0; i < 2; ++i) {
      gload_lds16(aga[i] + kt, &Alds[buf][ldso[i]]);
      gload_lds16(bga[i] + kt, &Blds[buf][ldso[i]]);
    }
  };
  auto COMPUTE = [&](int buf) {
    bf16x8 af[4], bfr[4];
#pragma unroll
    for (int mi = 0; mi < 4; ++mi)
      af[mi] = ldsr128(&Alds[buf][(wm + mi * 16 + l16) * 32 + lk * 8]);
#pragma unroll
    for (int nj = 0; nj < 4; ++nj)
      bfr[nj] = ldsr128(&Blds[buf][(wn + nj * 16 + l16) * 32 + lk * 8]);
    asm volatile("s_waitcnt lgkmcnt(0)" ::: "memory");
    __builtin_amdgcn_sched_barrier(0);
#pragma unroll
    for (int mi = 0; mi < 4; ++mi)
#pragma unroll
      for (int nj = 0; nj < 4; ++nj)
        acc[mi][nj] = __builtin_amdgcn_mfma_f32_16x16x32_bf16(
            af[mi], bfr[nj], acc[mi][nj], 0, 0, 0);
  };

  STAGE(0, 0);
  __syncthreads();
  int cur = 0;
  for (int t = 0; t < 31; ++t) {
    STAGE((t + 1) * 32, cur ^ 1);
    COMPUTE(cur);
    __syncthreads();
    cur ^= 1;
  }
  COMPUTE(cur);

#pragma unroll
  for (int mi = 0; mi < 4; ++mi) {
#pragma unroll
    for (int r = 0; r < 4; ++r) {
      const int rl = m0 + wm + mi * 16 + lk * 4 + r;
      if (rl >= count) continue;
      unsigned short* hrow = H + (size_t)(offset + rl) * FC;
#pragma unroll
      for (int nj = 0; nj < 4; ++nj) {
        const int c = n0 + wn + nj * 16 + l16;
        float v = acc[mi][nj][r] + b1[e * 4096 + f0 + c];
        hrow[c] = f2bf(v > 0.f ? v : 0.f);
      }
    }
  }
}

// ------- GEMM2: P[ks][slot][d] (+)= slice_ks(H[slot] @ W2t[e]) (+ b2) -------
// split-K=2, private partial buffers, no atomics.
__global__ __launch_bounds__(256) void gemm2_kernel(
    const unsigned short* __restrict__ H,
    const unsigned short* __restrict__ W2t, const float* __restrict__ b2,
    const int* __restrict__ counts, const int* __restrict__ offsets,
    float* __restrict__ P, int FC, int firstChunk) {
  const int e = blockIdx.z >> 1;
  const int ks = blockIdx.z & 1;
  const int count = counts[e];
  const int m0 = blockIdx.y * 128;
  if (m0 >= count) return;
  const int offset = offsets[e];
  const int n0 = blockIdx.x * 128;
  const int KS = FC / 2;
  const int kb = ks * KS;
  float* Pb = P + (size_t)ks * 8192 * 1024;

  __shared__ __align__(16) unsigned short Alds[2][128 * 32];
  __shared__ __align__(16) unsigned short Blds[2][128 * 32];

  const int tid = threadIdx.x;
  const int lane = tid & 63;
  const int wave = tid >> 6;
  const int srow = lane >> 2;
  const int skp = (lane & 3) * 8;
  const unsigned short* aga[2];
  const unsigned short* bga[2];
  int ldso[2];
#pragma unroll
  for (int i = 0; i < 2; ++i) {
    int ar = m0 + wave * 32 + i * 16 + srow;
    if (ar >= count) ar = count - 1;
    aga[i] = H + (size_t)(offset + ar) * FC + kb + skp;
    bga[i] = W2t + ((size_t)e * 1024 + n0 + wave * 32 + i * 16 + srow) * FC + kb + skp;
    ldso[i] = (wave * 32 + i * 16) * 32;
  }

  const int wm = (wave >> 1) * 64;
  const int wn = (wave & 1) * 64;
  const int l16 = lane & 15;
  const int lk = lane >> 4;

  f32x4 acc[4][4] = {};

  auto STAGE = [&](int kt, int buf) {
#pragma unroll
    for (int i = 0; i < 2; ++i) {
      gload_lds16(aga[i] + kt, &Alds[buf][ldso[i]]);
      gload_lds16(bga[i] + kt, &Blds[buf][ldso[i]]);
    }
  };
  auto COMPUTE = [&](int buf) {
    bf16x8 af[4], bfr[4];
#pragma unroll
    for (int mi = 0; mi < 4; ++mi)
      af[mi] = ldsr128(&Alds[buf][(wm + mi * 16 + l16) * 32 + lk * 8]);
#pragma unroll
    for (int nj = 0; nj < 4; ++nj)
      bfr[nj] = ldsr128(&Blds[buf][(wn + nj * 16 + l16) * 32 + lk * 8]);
    asm volatile("s_waitcnt lgkmcnt(0)" ::: "memory");
    __builtin_amdgcn_sched_barrier(0);
#pragma unroll
    for (int mi = 0; mi < 4; ++mi)
#pragma unroll
      for (int nj = 0; nj < 4; ++nj)
        acc[mi][nj] = __builtin_amdgcn_mfma_f32_16x16x32_bf16(
            af[mi], bfr[nj], acc[mi][nj], 0, 0, 0);
  };

  const int NT = KS / 32;
  STAGE(0, 0);
  __syncthreads();
  int cur = 0;
  for (int t = 0; t < NT - 1; ++t) {
    STAGE((t + 1) * 32, cur ^ 1);
    COMPUTE(cur);
    __syncthreads();
    cur ^= 1;
  }
  COMPUTE(cur);

#pragma unroll
  for (int mi = 0; mi < 4; ++mi) {
#pragma unroll
    for (int r = 0; r < 4; ++r) {
      const int rl = m0 + wm + mi * 16 + lk * 4 + r;
      if (rl >= count) continue;
      float* prow = Pb + (size_t)(offset + rl) * 1024;
#pragma unroll
      for (int nj = 0; nj < 4; ++nj) {
        const int c = n0 + wn + nj * 16 + l16;
        float v = acc[mi][nj][r];
        if (ks == 0 && firstChunk) v += b2[e * 1024 + c];
        if (firstChunk)
          prow[c] = v;
        else
          prow[c] += v;
      }
    }
  }
}

// ---------------- combine: out[t] = w0*(P0[s0]+P1[s0]) + w1*(...) ----------
__global__ __launch_bounds__(256) void combine_kernel(
    const float* __restrict__ P, const int* __restrict__ tok_slot,
    const float* __restrict__ tok_w, float* __restrict__ out) {
  const int t = blockIdx.x;
  const int d = threadIdx.x * 4;
  const int s0 = tok_slot[2 * t];
  const int s1 = tok_slot[2 * t + 1];
  const float w0 = tok_w[2 * t];
  const float w1 = tok_w[2 * t + 1];
  const float4 a0 = *(const float4*)&P[(size_t)s0 * 1024 + d];
  const float4 a1 = *(const float4*)&P[(size_t)(8192 + s0) * 1024 + d];
  const float4 c0 = *(const float4*)&P[(size_t)s1 * 1024 + d];
  const float4 c1 = *(const float4*)&P[(size_t)(8192 + s1) * 1024 + d];
  float4 r;
  r.x = w0 * (a0.x + a1.x) + w1 * (c0.x + c1.x);
  r.y = w0 * (a0.y + a1.y) + w1 * (c0.y + c1.y);
  r.z = w0 * (a0.z + a1.z) + w1 * (c0.z + c1.z);
  r.w = w0 * (a0.w + a1.w) + w1 * (c0.w + c1.w);
  *(float4*)&out[(size_t)t * 1024 + d] = r;
}

extern "C" void kernel_launch(void* const* d_in, const int* in_sizes, int n_in,
                              void* d_out, int out_size, void* d_ws,
                              size_t ws_size, hipStream_t stream) {
  const float* x = (const float*)d_in[0];
  const float* Wg = (const float*)d_in[1];
  const float* bg = (const float*)d_in[2];
  const float* W1 = (const float*)d_in[3];
  const float* b1 = (const float*)d_in[4];
  const float* W2 = (const float*)d_in[5];
  const float* b2 = (const float*)d_in[6];
  float* out = (float*)d_out;

  char* w = (char*)d_ws;
  int* counts = (int*)w;
  int* offsets = counts + 16;
  int* cursors = counts + 32;
  int* tok_e = (int*)(w + 1024);
  float* tok_w = (float*)(w + 1024 + 32768);
  int* pair_token = (int*)(w + 1024 + 65536);
  int* tok_slot = (int*)(w + 1024 + 98304);
  unsigned short* xb = (unsigned short*)(w + 256 * 1024);  // 8MB
  float* P = (float*)(w + 256 * 1024 + 8 * 1024 * 1024);   // 64MB (2x8192x1024 f32)
  char* big = w + 256 * 1024 + 8 * 1024 * 1024 + 64 * 1024 * 1024;
  const size_t avail =
      ws_size - (256 * 1024 + 8 * 1024 * 1024 + 64 * 1024 * 1024);

  int FC = 4096;
  while (FC > 256 && (size_t)FC * 49152 > avail) FC >>= 1;

  unsigned short* W1t = (unsigned short*)big;
  unsigned short* W2t = W1t + (size_t)8 * FC * 1024;
  unsigned short* Hc = W2t + (size_t)8 * 1024 * FC;

  hipMemsetAsync(counts, 0, 64, stream);

  gate_kernel<<<1024, 256, 0, stream>>>(x, Wg, bg, tok_e, tok_w, counts);
  scan_kernel<<<1, 64, 0, stream>>>(counts, offsets, cursors);
  scatter_kernel<<<16, 256, 0, stream>>>(tok_e, cursors, pair_token, tok_slot);
  xconv_kernel<<<4096, 256, 0, stream>>>(x, xb);

  for (int f0 = 0; f0 < 4096; f0 += FC) {
    transW1_kernel<<<dim3(FC / 64, 8, 8), 256, 0, stream>>>(W1, W1t, FC, f0);
    transW2_kernel<<<dim3(16, FC / 128, 8), 256, 0, stream>>>(W2, W2t, FC, f0);
    gemm1_kernel<<<dim3(FC / 128, 32, 8), 256, 0, stream>>>(
        xb, W1t, b1, counts, offsets, pair_token, Hc, FC, f0);
    gemm2_kernel<<<dim3(8, 32, 16), 256, 0, stream>>>(
        Hc, W2t, b2, counts, offsets, P, FC, f0 == 0 ? 1 : 0);
  }
  combine_kernel<<<4096, 256, 0, stream>>>(P, tok_slot, tok_w, out);
}

// Round 5
// 484.075 us; speedup vs baseline: 1.1528x; 1.0654x over previous
//
#include <hip/hip_runtime.h>
#include <hip/hip_bf16.h>

// SimpleMoE: B=2,S=2048 -> 4096 tokens, DIM=1024, FF=4096, E=8, top-2 routing.
// Round 5: expert-per-XCD block pinning (e = bid&7) for L2 reuse of weight
// slices + token rows; split-K dropped (single fp32 partial buffer P).

typedef __attribute__((ext_vector_type(8))) short bf16x8;
typedef __attribute__((ext_vector_type(4))) float f32x4;

__device__ __forceinline__ unsigned short f2bf(float f) {
  unsigned u = __builtin_bit_cast(unsigned, f);
  u += 0x7FFFu + ((u >> 16) & 1u);
  return (unsigned short)(u >> 16);
}

__device__ __forceinline__ void gload_lds16(const void* g, void* l) {
  __builtin_amdgcn_global_load_lds(
      (const __attribute__((address_space(1))) unsigned int*)g,
      (__attribute__((address_space(3))) unsigned int*)l, 16, 0, 0);
}

// inline-asm LDS read: keeps the compiler from serializing ds_read behind
// in-flight global_load_lds (false alias) with a vmcnt(0).
__device__ __forceinline__ bf16x8 ldsr128(const unsigned short* p) {
  bf16x8 r;
  unsigned a = (unsigned)(unsigned long long)p;
  asm volatile("ds_read_b128 %0, %1" : "=v"(r) : "v"(a));
  return r;
}

// ---------------- gate: logits (fp64), softmax, top-2, counts ----------------
__global__ __launch_bounds__(256) void gate_kernel(
    const float* __restrict__ x, const float* __restrict__ Wg,
    const float* __restrict__ bg, int* __restrict__ tok_e,
    float* __restrict__ tok_w, int* __restrict__ counts) {
  const int wave = threadIdx.x >> 6;
  const int lane = threadIdx.x & 63;
  const int t = blockIdx.x * 4 + wave;
  const float* xr = x + (size_t)t * 1024;
  double acc[8] = {0, 0, 0, 0, 0, 0, 0, 0};
  for (int i = 0; i < 16; ++i) {
    const int d = i * 64 + lane;
    const double xv = (double)xr[d];
    const float* wr = Wg + d * 8;
#pragma unroll
    for (int e = 0; e < 8; ++e) acc[e] += xv * (double)wr[e];
  }
#pragma unroll
  for (int e = 0; e < 8; ++e) {
    double v = acc[e];
#pragma unroll
    for (int off = 32; off > 0; off >>= 1) v += __shfl_xor(v, off, 64);
    acc[e] = v + (double)bg[e];
  }
  if (lane == 0) {
    int e0 = 0;
#pragma unroll
    for (int e = 1; e < 8; ++e)
      if (acc[e] > acc[e0]) e0 = e;
    int e1 = (e0 == 0) ? 1 : 0;
#pragma unroll
    for (int e = 0; e < 8; ++e) {
      if (e != e0 && acc[e] > acc[e1]) e1 = e;
    }
    const double m = acc[e0];
    double s = 0.0;
#pragma unroll
    for (int e = 0; e < 8; ++e) s += exp(acc[e] - m);
    const double p0 = exp(acc[e0] - m) / s;
    const double p1 = exp(acc[e1] - m) / s;
    const double den = p0 + p1 + 1e-9;
    tok_e[2 * t] = e0;
    tok_e[2 * t + 1] = e1;
    tok_w[2 * t] = (float)(p0 / den);
    tok_w[2 * t + 1] = (float)(p1 / den);
    atomicAdd(&counts[e0], 1);
    atomicAdd(&counts[e1], 1);
  }
}

__global__ void scan_kernel(const int* __restrict__ counts,
                            int* __restrict__ offsets,
                            int* __restrict__ cursors) {
  if (threadIdx.x == 0) {
    int s = 0;
    for (int e = 0; e < 8; ++e) {
      offsets[e] = s;
      cursors[e] = s;
      s += counts[e];
    }
  }
}

__global__ __launch_bounds__(256) void scatter_kernel(
    const int* __restrict__ tok_e, int* __restrict__ cursors,
    int* __restrict__ pair_token, int* __restrict__ tok_slot) {
  const int t = blockIdx.x * 256 + threadIdx.x;
  if (t >= 4096) return;
#pragma unroll
  for (int j = 0; j < 2; ++j) {
    const int e = tok_e[2 * t + j];
    const int slot = atomicAdd(&cursors[e], 1);
    pair_token[slot] = t;
    tok_slot[2 * t + j] = slot;
  }
}

// ---------------- x -> bf16 ----------------
__global__ __launch_bounds__(256) void xconv_kernel(
    const float* __restrict__ x, unsigned short* __restrict__ xb) {
  const size_t i = ((size_t)blockIdx.x * 256 + threadIdx.x) * 4;
  const float4 v = *(const float4*)(x + i);
  ushort4 pk;
  pk.x = f2bf(v.x); pk.y = f2bf(v.y); pk.z = f2bf(v.z); pk.w = f2bf(v.w);
  *(ushort4*)(xb + i) = pk;
}

// ---------------- W1[e][k][f] -> W1t[e][f_local][k] (bf16) ----------------
__global__ __launch_bounds__(256) void transW1_kernel(
    const float* __restrict__ W1, unsigned short* __restrict__ W1t, int FC,
    int f0) {
  const int e = blockIdx.z;
  const int fl = blockIdx.x * 64 + (threadIdx.x & 63);
  const int kg = threadIdx.x >> 6;
  const int kbase = (blockIdx.y * 4 + kg) * 32;
  const float* src = W1 + ((size_t)e * 1024 + kbase) * 4096 + f0 + fl;
  unsigned short* dst = W1t + ((size_t)e * FC + fl) * 1024 + kbase;
  for (int i = 0; i < 8; ++i) {
    ushort4 pk;
    pk.x = f2bf(src[(size_t)(i * 4 + 0) * 4096]);
    pk.y = f2bf(src[(size_t)(i * 4 + 1) * 4096]);
    pk.z = f2bf(src[(size_t)(i * 4 + 2) * 4096]);
    pk.w = f2bf(src[(size_t)(i * 4 + 3) * 4096]);
    *(ushort4*)&dst[i * 4] = pk;
  }
}

// ---------------- W2[e][f][d] -> W2t[e][d][f_local] (bf16) ----------------
__global__ __launch_bounds__(256) void transW2_kernel(
    const float* __restrict__ W2, unsigned short* __restrict__ W2t, int FC,
    int f0) {
  const int e = blockIdx.z;
  const int dl = blockIdx.x * 64 + (threadIdx.x & 63);
  const int fg = threadIdx.x >> 6;
  const int fbase = (blockIdx.y * 4 + fg) * 32;
  const float* src = W2 + ((size_t)e * 4096 + f0 + fbase) * 1024 + dl;
  unsigned short* dst = W2t + ((size_t)e * 1024 + dl) * FC + fbase;
  for (int i = 0; i < 8; ++i) {
    ushort4 pk;
    pk.x = f2bf(src[(size_t)(i * 4 + 0) * 1024]);
    pk.y = f2bf(src[(size_t)(i * 4 + 1) * 1024]);
    pk.z = f2bf(src[(size_t)(i * 4 + 2) * 1024]);
    pk.w = f2bf(src[(size_t)(i * 4 + 3) * 1024]);
    *(ushort4*)&dst[i * 4] = pk;
  }
}

// ---------------- GEMM1: H[slot][n] = relu(xb[tok] @ W1t[e] + b1) -----------
// 1D grid, e = bid&7 (XCD pinning), then m-tile / n-tile with n fastest.
__global__ __launch_bounds__(256) void gemm1_kernel(
    const unsigned short* __restrict__ xb,
    const unsigned short* __restrict__ W1t, const float* __restrict__ b1,
    const int* __restrict__ counts, const int* __restrict__ offsets,
    const int* __restrict__ pair_token, unsigned short* __restrict__ H, int FC,
    int f0, int NT) {
  const int bid = blockIdx.x;
  const int e = bid & 7;
  const int lid = bid >> 3;
  const int n0 = (lid % NT) * 128;
  const int m0 = (lid / NT) * 128;
  const int count = counts[e];
  if (m0 >= count) return;
  const int offset = offsets[e];

  __shared__ __align__(16) unsigned short Alds[2][128 * 32];
  __shared__ __align__(16) unsigned short Blds[2][128 * 32];
  __shared__ int toklds[128];

  const int tid = threadIdx.x;
  if (tid < 128) {
    int r = m0 + tid;
    if (r >= count) r = count - 1;
    toklds[tid] = pair_token[offset + r];
  }
  __syncthreads();

  const int lane = tid & 63;
  const int wave = tid >> 6;
  const int srow = lane >> 2;
  const int skp = (lane & 3) * 8;
  const unsigned short* aga[2];
  const unsigned short* bga[2];
  int ldso[2];
#pragma unroll
  for (int i = 0; i < 2; ++i) {
    const int ar = wave * 32 + i * 16 + srow;
    aga[i] = xb + (size_t)toklds[ar] * 1024 + skp;
    bga[i] = W1t + ((size_t)e * FC + n0 + wave * 32 + i * 16 + srow) * 1024 + skp;
    ldso[i] = (wave * 32 + i * 16) * 32;
  }

  const int wm = (wave >> 1) * 64;
  const int wn = (wave & 1) * 64;
  const int l16 = lane & 15;
  const int lk = lane >> 4;

  f32x4 acc[4][4] = {};

  auto STAGE = [&](int kt, int buf) {
#pragma unroll
    for (int i = 0; i < 2; ++i) {
      gload_lds16(aga[i] + kt, &Alds[buf][ldso[i]]);
      gload_lds16(bga[i] + kt, &Blds[buf][ldso[i]]);
    }
  };
  auto COMPUTE = [&](int buf) {
    bf16x8 af[4], bfr[4];
#pragma unroll
    for (int mi = 0; mi < 4; ++mi)
      af[mi] = ldsr128(&Alds[buf][(wm + mi * 16 + l16) * 32 + lk * 8]);
#pragma unroll
    for (int nj = 0; nj < 4; ++nj)
      bfr[nj] = ldsr128(&Blds[buf][(wn + nj * 16 + l16) * 32 + lk * 8]);
    asm volatile("s_waitcnt lgkmcnt(0)" ::: "memory");
    __builtin_amdgcn_sched_barrier(0);
#pragma unroll
    for (int mi = 0; mi < 4; ++mi)
#pragma unroll
      for (int nj = 0; nj < 4; ++nj)
        acc[mi][nj] = __builtin_amdgcn_mfma_f32_16x16x32_bf16(
            af[mi], bfr[nj], acc[mi][nj], 0, 0, 0);
  };

  STAGE(0, 0);
  __syncthreads();
  int cur = 0;
  for (int t = 0; t < 31; ++t) {
    STAGE((t + 1) * 32, cur ^ 1);
    COMPUTE(cur);
    __syncthreads();
    cur ^= 1;
  }
  COMPUTE(cur);

#pragma unroll
  for (int mi = 0; mi < 4; ++mi) {
#pragma unroll
    for (int r = 0; r < 4; ++r) {
      const int rl = m0 + wm + mi * 16 + lk * 4 + r;
      if (rl >= count) continue;
      unsigned short* hrow = H + (size_t)(offset + rl) * FC;
#pragma unroll
      for (int nj = 0; nj < 4; ++nj) {
        const int c = n0 + wn + nj * 16 + l16;
        float v = acc[mi][nj][r] + b1[e * 4096 + f0 + c];
        hrow[c] = f2bf(v > 0.f ? v : 0.f);
      }
    }
  }
}

// ------- GEMM2: P[slot][d] (+)= H[slot] @ W2t[e] (+ b2), no split-K ---------
__global__ __launch_bounds__(256) void gemm2_kernel(
    const unsigned short* __restrict__ H,
    const unsigned short* __restrict__ W2t, const float* __restrict__ b2,
    const int* __restrict__ counts, const int* __restrict__ offsets,
    float* __restrict__ P, int FC, int firstChunk) {
  const int bid = blockIdx.x;
  const int e = bid & 7;
  const int lid = bid >> 3;
  const int n0 = (lid & 7) * 128;   // 8 n-tiles (N=1024)
  const int m0 = (lid >> 3) * 128;  // 32 m-tiles
  const int count = counts[e];
  if (m0 >= count) return;
  const int offset = offsets[e];

  __shared__ __align__(16) unsigned short Alds[2][128 * 32];
  __shared__ __align__(16) unsigned short Blds[2][128 * 32];

  const int tid = threadIdx.x;
  const int lane = tid & 63;
  const int wave = tid >> 6;
  const int srow = lane >> 2;
  const int skp = (lane & 3) * 8;
  const unsigned short* aga[2];
  const unsigned short* bga[2];
  int ldso[2];
#pragma unroll
  for (int i = 0; i < 2; ++i) {
    int ar = m0 + wave * 32 + i * 16 + srow;
    if (ar >= count) ar = count - 1;
    aga[i] = H + (size_t)(offset + ar) * FC + skp;
    bga[i] = W2t + ((size_t)e * 1024 + n0 + wave * 32 + i * 16 + srow) * FC + skp;
    ldso[i] = (wave * 32 + i * 16) * 32;
  }

  const int wm = (wave >> 1) * 64;
  const int wn = (wave & 1) * 64;
  const int l16 = lane & 15;
  const int lk = lane >> 4;

  f32x4 acc[4][4] = {};

  auto STAGE = [&](int kt, int buf) {
#pragma unroll
    for (int i = 0; i < 2; ++i) {
      gload_lds16(aga[i] + kt, &Alds[buf][ldso[i]]);
      gload_lds16(bga[i] + kt, &Blds[buf][ldso[i]]);
    }
  };
  auto COMPUTE = [&](int buf) {
    bf16x8 af[4], bfr[4];
#pragma unroll
    for (int mi = 0; mi < 4; ++mi)
      af[mi] = ldsr128(&Alds[buf][(wm + mi * 16 + l16) * 32 + lk * 8]);
#pragma unroll
    for (int nj = 0; nj < 4; ++nj)
      bfr[nj] = ldsr128(&Blds[buf][(wn + nj * 16 + l16) * 32 + lk * 8]);
    asm volatile("s_waitcnt lgkmcnt(0)" ::: "memory");
    __builtin_amdgcn_sched_barrier(0);
#pragma unroll
    for (int mi = 0; mi < 4; ++mi)
#pragma unroll
      for (int nj = 0; nj < 4; ++nj)
        acc[mi][nj] = __builtin_amdgcn_mfma_f32_16x16x32_bf16(
            af[mi], bfr[nj], acc[mi][nj], 0, 0, 0);
  };

  const int NTk = FC / 32;
  STAGE(0, 0);
  __syncthreads();
  int cur = 0;
  for (int t = 0; t < NTk - 1; ++t) {
    STAGE((t + 1) * 32, cur ^ 1);
    COMPUTE(cur);
    __syncthreads();
    cur ^= 1;
  }
  COMPUTE(cur);

#pragma unroll
  for (int mi = 0; mi < 4; ++mi) {
#pragma unroll
    for (int r = 0; r < 4; ++r) {
      const int rl = m0 + wm + mi * 16 + lk * 4 + r;
      if (rl >= count) continue;
      float* prow = P + (size_t)(offset + rl) * 1024;
#pragma unroll
      for (int nj = 0; nj < 4; ++nj) {
        const int c = n0 + wn + nj * 16 + l16;
        float v = acc[mi][nj][r];
        if (firstChunk) {
          prow[c] = v + b2[e * 1024 + c];
        } else {
          prow[c] += v;
        }
      }
    }
  }
}

// ---------------- combine: out[t] = w0*P[s0] + w1*P[s1] ----------------
__global__ __launch_bounds__(256) void combine_kernel(
    const float* __restrict__ P, const int* __restrict__ tok_slot,
    const float* __restrict__ tok_w, float* __restrict__ out) {
  const int t = blockIdx.x;
  const int d = threadIdx.x * 4;
  const int s0 = tok_slot[2 * t];
  const int s1 = tok_slot[2 * t + 1];
  const float w0 = tok_w[2 * t];
  const float w1 = tok_w[2 * t + 1];
  const float4 a = *(const float4*)&P[(size_t)s0 * 1024 + d];
  const float4 b = *(const float4*)&P[(size_t)s1 * 1024 + d];
  float4 r;
  r.x = w0 * a.x + w1 * b.x;
  r.y = w0 * a.y + w1 * b.y;
  r.z = w0 * a.z + w1 * b.z;
  r.w = w0 * a.w + w1 * b.w;
  *(float4*)&out[(size_t)t * 1024 + d] = r;
}

extern "C" void kernel_launch(void* const* d_in, const int* in_sizes, int n_in,
                              void* d_out, int out_size, void* d_ws,
                              size_t ws_size, hipStream_t stream) {
  const float* x = (const float*)d_in[0];
  const float* Wg = (const float*)d_in[1];
  const float* bg = (const float*)d_in[2];
  const float* W1 = (const float*)d_in[3];
  const float* b1 = (const float*)d_in[4];
  const float* W2 = (const float*)d_in[5];
  const float* b2 = (const float*)d_in[6];
  float* out = (float*)d_out;

  char* w = (char*)d_ws;
  int* counts = (int*)w;
  int* offsets = counts + 16;
  int* cursors = counts + 32;
  int* tok_e = (int*)(w + 1024);
  float* tok_w = (float*)(w + 1024 + 32768);
  int* pair_token = (int*)(w + 1024 + 65536);
  int* tok_slot = (int*)(w + 1024 + 98304);
  unsigned short* xb = (unsigned short*)(w + 256 * 1024);  // 8MB
  float* P = (float*)(w + 256 * 1024 + 8 * 1024 * 1024);   // 32MB (8192x1024 f32)
  char* big = w + 256 * 1024 + 8 * 1024 * 1024 + 32 * 1024 * 1024;
  const size_t avail =
      ws_size - (256 * 1024 + 8 * 1024 * 1024 + 32 * 1024 * 1024);

  // per-chunk: W1t 16384*FC + W2t 16384*FC + H 16384*FC bytes
  int FC = 4096;
  while (FC > 256 && (size_t)FC * 49152 > avail) FC >>= 1;

  unsigned short* W1t = (unsigned short*)big;
  unsigned short* W2t = W1t + (size_t)8 * FC * 1024;
  unsigned short* Hc = W2t + (size_t)8 * 1024 * FC;

  hipMemsetAsync(counts, 0, 64, stream);

  gate_kernel<<<1024, 256, 0, stream>>>(x, Wg, bg, tok_e, tok_w, counts);
  scan_kernel<<<1, 64, 0, stream>>>(counts, offsets, cursors);
  scatter_kernel<<<16, 256, 0, stream>>>(tok_e, cursors, pair_token, tok_slot);
  xconv_kernel<<<4096, 256, 0, stream>>>(x, xb);

  const int NT1 = FC / 128;
  for (int f0 = 0; f0 < 4096; f0 += FC) {
    transW1_kernel<<<dim3(FC / 64, 8, 8), 256, 0, stream>>>(W1, W1t, FC, f0);
    transW2_kernel<<<dim3(16, FC / 128, 8), 256, 0, stream>>>(W2, W2t, FC, f0);
    gemm1_kernel<<<8 * NT1 * 32, 256, 0, stream>>>(
        xb, W1t, b1, counts, offsets, pair_token, Hc, FC, f0, NT1);
    gemm2_kernel<<<8 * 8 * 32, 256, 0, stream>>>(
        Hc, W2t, b2, counts, offsets, P, FC, f0 == 0 ? 1 : 0);
  }
  combine_kernel<<<4096, 256, 0, stream>>>(P, tok_slot, tok_w, out);
}